// Round 15
// baseline (9041.698 us; speedup 1.0000x reference)
//
#include <hip/hip_runtime.h>
#include <hip/hip_bf16.h>
#include <stdint.h>

// Problem constants (fixed by the reference): T=512, B=64, IN=H=1024, L=2
#define TT 512
#define BB 64
#define HH 1024
#define BH 65536    // B*H elements
#define KD 2048     // IN+H == H+H

typedef __attribute__((ext_vector_type(8))) short short8;
typedef __attribute__((ext_vector_type(4))) float f32x4;

__device__ __forceinline__ unsigned short f2bf(float f) {
  union { float f; unsigned int u; } v; v.f = f;
  unsigned int r = v.u + 0x7fffu + ((v.u >> 16) & 1u);  // RNE
  return (unsigned short)(r >> 16);
}
__device__ __forceinline__ float ftanhf(float x){ return 1.0f - 2.0f / (__expf(2.0f * x) + 1.0f); }

// ---------------- x -> bf16 ----------------
__global__ void cvt_x_kernel(const float* __restrict__ x, unsigned short* __restrict__ xbf) {
  const int n4 = (TT * BB * 1024) / 4;
  int stride = gridDim.x * blockDim.x;
  for (int i = blockIdx.x * blockDim.x + threadIdx.x; i < n4; i += stride) {
    float4 v = ((const float4*)x)[i];
    unsigned long long p = (unsigned long long)f2bf(v.x)
        | ((unsigned long long)f2bf(v.y) << 16)
        | ((unsigned long long)f2bf(v.z) << 32)
        | ((unsigned long long)f2bf(v.w) << 48);
    ((unsigned long long*)xbf)[i] = p;
  }
}

// ---------------- W [4096][2048] f32 -> bf16, LDS-image layout ----------------
// Ws[g][kk 0..63][nrow 0..31][hi 0..3][8 bf16]  (16B chunks; 128 KB per slice g)
__global__ void cvt_w_kernel(const float* __restrict__ W, unsigned short* __restrict__ Ws) {
  int idx = blockIdx.x * blockDim.x + threadIdx.x;   // < 128*64*32*4 = 1,048,576
  int hi = idx & 3;
  int nr = (idx >> 2) & 31;
  int kk = (idx >> 7) & 63;
  int g  = idx >> 13;
  int q  = (nr >> 2) & 3;
  int nt = nr >> 4;
  int jl = nr & 3;
  int grow = (q << 10) + (g << 3) + (nt << 2) + jl;
  int k = ((kk < 32) ? (kk << 5) : (1024 + ((kk - 32) << 5))) + (hi << 3);
  const float* src = W + (size_t)grow * KD + k;
  float4 v0 = ((const float4*)src)[0];
  float4 v1 = ((const float4*)src)[1];
  unsigned long long p0 = (unsigned long long)f2bf(v0.x)
      | ((unsigned long long)f2bf(v0.y) << 16)
      | ((unsigned long long)f2bf(v0.z) << 32)
      | ((unsigned long long)f2bf(v0.w) << 48);
  unsigned long long p1 = (unsigned long long)f2bf(v1.x)
      | ((unsigned long long)f2bf(v1.y) << 16)
      | ((unsigned long long)f2bf(v1.z) << 32)
      | ((unsigned long long)f2bf(v1.w) << 48);
  unsigned long long* dst = (unsigned long long*)(Ws + ((size_t)g << 16) + (kk << 10) + (nr << 5) + (hi << 3));
  dst[0] = p0;
  dst[1] = p1;
}

// ---------------- initial h -> hist slot 0 ----------------
__global__ void init_state_kernel(const float* __restrict__ h0in,
                                  unsigned short* h0s0, unsigned short* h1s0) {
  int i = blockIdx.x * blockDim.x + threadIdx.x;  // < BH
  h0s0[i] = f2bf(h0in[i]);
  h1s0[i] = f2bf(h0in[BH + i]);
}

#define GLD(p)    __hip_atomic_load((p),  __ATOMIC_RELAXED, __HIP_MEMORY_SCOPE_AGENT)
#define GST(p, v) __hip_atomic_store((p), (v), __ATOMIC_RELAXED, __HIP_MEMORY_SCOPE_AGENT)

// spin until the 8 sub-counters (256B apart) sum to 128
__device__ __forceinline__ void poll128(int* base) {
  for (;;) {
    int s = 0;
#pragma unroll
    for (int j = 0; j < 8; j++)
      s += GLD(base + (j << 6));
    if (s >= 128) return;
    __builtin_amdgcn_s_sleep(1);
  }
}

// ---------------- persistent 2-layer LSTM, v10: quad tags + monotone cross-layer gate ----
// 256 blocks x 512 threads, 1 block/CU. Blocks 0-127: layer0, 128-255: layer1.
// Waves 0-3 (A): dependency-free GEMM one step ahead (L0: x[s+1]; L1: h0[s+2]
// gated by MONOTONE counter cnt0[s+1] — immune to L0 run-ahead, unlike v9's
// ring-equality gate which livelocked) -> partials into LDS dbuf pbuf[(s+1)&1].
// Waves 4-7 (B): tight recurrence, no global barrier. INTRA-layer h readiness
// via per-(quad,mt) ring-4 tag words (64B lines): producer wave mt of block g,
// after per-wave s_waitcnt vmcnt(0) on its sc1 h-stores, byte-stores (s+1)&255
// into byte g&3 of tag[(s+1)&3][mt][g>>2]. Intra-layer skew <= 1 step (all-to-
// all K dependency) => ring-4 exact-equality is alias-free WITHIN a layer.
// Consumers prefetch 32 tag words a step ahead; per-frag: check -> fence ->
// load -> MFMA, skewed to start at own quad. Cross-layer: L0 blocks publish
// cnt0[s] (tid0 atomicAdd after the end-of-step LDS barrier, which orders all
// B-wave drains); h0hist is full history so unbounded L0 lead is data-safe.
__global__ __launch_bounds__(512, 2) void lstm_persist(
    const unsigned short* __restrict__ W0s, const unsigned short* __restrict__ W1s,
    const float* __restrict__ b0, const float* __restrict__ b1,
    const unsigned short* __restrict__ xbf,
    unsigned short* h0hist, unsigned short* h1hist,
    const float* __restrict__ c0in, float* out,
    unsigned int* tag0, unsigned int* tag1, int* cnt0)
{
  __shared__ short8 wlds[8192];            // 128 KB: [kk 0..63][nrow 0..31][hi 0..3]
  __shared__ f32x4 pbuf[2][4][2][64];      // 16 KB partial double-buffer
  const int tid = threadIdx.x;
  const int bid = blockIdx.x;
  const int layer = bid >> 7;
  const int g = bid & 127;

  const unsigned short* Ws = layer ? W1s : W0s;
  const float* bias = layer ? b1 : b0;

  // ---- stage weight slice once: linear 128KB copy ----
  {
    const short8* wsrc = (const short8*)(Ws + ((size_t)g << 16));
#pragma unroll
    for (int it = 0; it < 16; it++)
      wlds[tid + (it << 9)] = wsrc[tid + (it << 9)];
  }

  // ---- wave / lane mapping ----
  const int lane = tid & 63;
  const int w  = tid >> 6;        // 0..7
  const bool isA = (w < 4);
  const int mt = w & 3;           // m-tile (batch)
  const int m0 = mt << 4;
  const int n  = lane & 15;
  const int hi = lane >> 4;
  const int q  = n >> 2;          // gate type of this lane's acc column
  const int jl = n & 3;
  const int jgb = (g << 3) + jl;  // h column base (nt=0); nt=1 -> +4
  const int skew = g >> 2;        // start K consumption at own quad
  const short8* bbase0 = wlds + ((n << 2) + hi);          // n-tile 0 rows 0..15
  const short8* bbase1 = wlds + (((16 + n) << 2) + hi);   // n-tile 1 rows 16..31
  const int rowoff = ((m0 + n) << 10) + (hi << 3);        // A-row base (elements)

  unsigned short* const myhist = (layer == 0) ? h0hist : h1hist;
  unsigned int* const mytag = (layer == 0) ? tag0 : tag1;
  // tag word (ring, mt, kk) at mytag + ((ring*4+mt)<<9) + (kk<<4)   [64B lines]

  // ---- B-wave state: biases + c registers for both n-tiles ----
  float creg[2][4];
  float blane0 = 0.f, blane1 = 0.f;
  if (!isA) {
    blane0 = bias[(q << 10) + jgb];
    blane1 = bias[(q << 10) + jgb + 4];
    if (n < 4) {
#pragma unroll
      for (int nt2 = 0; nt2 < 2; nt2++)
#pragma unroll
        for (int r = 0; r < 4; r++) {
          int m = m0 + (hi << 2) + r;
          creg[nt2][r] = c0in[(size_t)layer * BH + (m << 10) + jgb + (nt2 << 2)];
        }
    }
  }
  __syncthreads();   // weights staged

  // ---- prologue ----
  unsigned int tv[32];
  if (isA) {
    // L1-A gate for partial[0] (needs h0hist[1]): monotone counter, no aliasing
    if (layer == 1) {
      if (lane == 0) poll128(cnt0);
      asm volatile("" ::: "memory");
    }
    const unsigned short* asrc = ((layer == 0) ? xbf : h0hist + (size_t)BH) + rowoff;
    short8 ha[8];
#pragma unroll
    for (int j = 0; j < 8; j++) ha[j] = *(const short8*)(asrc + (j << 5));
    f32x4 a0 = {0.f, 0.f, 0.f, 0.f}, a1 = {0.f, 0.f, 0.f, 0.f};
#pragma unroll
    for (int blk = 0; blk < 4; blk++) {
#pragma unroll
      for (int j = 0; j < 8; j++) {
        int kk = (blk << 3) + j;
        a0 = __builtin_amdgcn_mfma_f32_16x16x32_bf16(ha[j], bbase0[kk << 7], a0, 0, 0, 0);
        a1 = __builtin_amdgcn_mfma_f32_16x16x32_bf16(ha[j], bbase1[kk << 7], a1, 0, 0, 0);
        if (blk < 3) ha[j] = *(const short8*)(asrc + ((kk + 8) << 5));
      }
    }
    pbuf[0][mt][0][lane] = a0;
    pbuf[0][mt][1][lane] = a1;
  } else {
    // B: prefetch tags for slot 0 (ring 0; init value 0 == expected)
    const unsigned int* tr = mytag + (mt << 9);
#pragma unroll
    for (int i = 0; i < 32; i++)
      tv[i] = (unsigned int)GLD((const int*)(tr + (((skew + i) & 31) << 4)));
  }
  __syncthreads();   // partial[0] sealed

  for (int s = 0; s < TT; s++) {
    float hsv[2][4];   // B: saved h outputs for deferred f32 out-stores

    if (isA) {
      // ---- A-compute for step s+1 into pbuf[(s+1)&1] ----
      if (s + 1 < TT) {
        if (layer == 1) {
          if (lane == 0) poll128(cnt0 + ((s + 1) << 9));   // h0hist[s+2] ready (monotone)
          asm volatile("" ::: "memory");
        }
        const unsigned short* asrc = ((layer == 0) ? xbf + (size_t)(s + 1) * BH
                                                   : h0hist + (size_t)(s + 2) * BH) + rowoff;
        short8 ha[8];
#pragma unroll
        for (int j = 0; j < 8; j++) ha[j] = *(const short8*)(asrc + (j << 5));
        f32x4 a0 = {0.f, 0.f, 0.f, 0.f}, a1 = {0.f, 0.f, 0.f, 0.f};
#pragma unroll
        for (int blk = 0; blk < 4; blk++) {
#pragma unroll
          for (int j = 0; j < 8; j++) {
            int kk = (blk << 3) + j;
            a0 = __builtin_amdgcn_mfma_f32_16x16x32_bf16(ha[j], bbase0[kk << 7], a0, 0, 0, 0);
            a1 = __builtin_amdgcn_mfma_f32_16x16x32_bf16(ha[j], bbase1[kk << 7], a1, 0, 0, 0);
            if (blk < 3) ha[j] = *(const short8*)(asrc + ((kk + 8) << 5));
          }
        }
        int buf = (s + 1) & 1;
        pbuf[buf][mt][0][lane] = a0;
        pbuf[buf][mt][1][lane] = a1;
      }
    } else {
      // ---- B: per-quad tag check (skewed, intra-layer only) -> frag load; MFMA ----
      unsigned int expv = (unsigned int)(s & 255) * 0x01010101u;
      const unsigned int* trow = mytag + ((((s & 3) << 2) + mt) << 9);
      f32x4 acc0 = pbuf[s & 1][mt][0][lane];
      f32x4 acc1 = pbuf[s & 1][mt][1][lane];
      const unsigned short* inB = myhist + (size_t)s * BH + rowoff;
      short8 ha[32];
#pragma unroll
      for (int i = 0; i < 32; i++) {
        int kk = (skew + i) & 31;
        unsigned int t = tv[i];
        while (t != expv) t = (unsigned int)GLD((const int*)(trow + (kk << 4)));
        asm volatile("" ::: "memory");
        ha[i] = *(const short8*)(inB + (kk << 5));
      }
#pragma unroll
      for (int i = 0; i < 32; i++) {
        int kk = (skew + i) & 31;
        acc0 = __builtin_amdgcn_mfma_f32_16x16x32_bf16(ha[i], bbase0[(32 + kk) << 7], acc0, 0, 0, 0);
        acc1 = __builtin_amdgcn_mfma_f32_16x16x32_bf16(ha[i], bbase1[(32 + kk) << 7], acc1, 0, 0, 0);
      }

      // ---- epilogue: activation, gather, state update, sc1 h-stores ----
      unsigned int* hb32 = (unsigned int*)(myhist + (size_t)(s + 1) * BH);
      const int srcl = (lane & 48) | jl;
#pragma unroll
      for (int nt2 = 0; nt2 < 2; nt2++) {
        f32x4 acc = nt2 ? acc1 : acc0;
        const int jg = jgb + (nt2 << 2);
        const float blane = nt2 ? blane1 : blane0;
#pragma unroll
        for (int r = 0; r < 4; r++) {
          float a = acc[r] + blane;
          float t = (q == 2) ? (a + a) : -a;
          float e = __expf(t);
          float act = (q == 2) ? (1.0f - 2.0f / (e + 1.0f)) : (1.0f / (1.0f + e));
          float vi = __shfl(act, srcl,      64);
          float vf = __shfl(act, srcl | 4,  64);
          float vg = __shfl(act, srcl | 8,  64);
          float vo = __shfl(act, srcl | 12, 64);
          float hn = 0.f;
          int m = m0 + (hi << 2) + r;
          int idx = (m << 10) + jg;
          if (n < 4) {
            float cn = vi * vg + vf * creg[nt2][r];
            hn = vo * ftanhf(cn);
            creg[nt2][r] = cn;
          }
          hsv[nt2][r] = hn;
          float hn2 = __shfl(hn, lane + 1, 64);
          if (n < 4 && (n & 1) == 0) {
            unsigned int pack = (unsigned int)f2bf(hn) | ((unsigned int)f2bf(hn2) << 16);
            GST(hb32 + (idx >> 1), pack);
          }
        }
      }

      // ---- publish: per-wave drain, then ONE tag byte store ----
      asm volatile("s_waitcnt vmcnt(0)" ::: "memory");
      if (lane == 0) {
        unsigned char* tb = (unsigned char*)(mytag + (((((s + 1) & 3) << 2) + mt) << 9)
                                             + ((g >> 2) << 4)) + (g & 3);
        GST(tb, (unsigned char)((s + 1) & 255));
      }
      // ---- prefetch tags for next consume slot (stale-tolerant) ----
      if (s + 1 < TT) {
        const unsigned int* tr2 = mytag + (((((s + 1) & 3) << 2) + mt) << 9);
#pragma unroll
        for (int i = 0; i < 32; i++)
          tv[i] = (unsigned int)GLD((const int*)(tr2 + (((skew + i) & 31) << 4)));
      }
    }

    // ---- LDS-only block barrier (seal pbuf; orders B drains for cnt publish) ----
    __builtin_amdgcn_sched_barrier(0);
    asm volatile("s_waitcnt lgkmcnt(0)" ::: "memory");
    __builtin_amdgcn_s_barrier();
    __builtin_amdgcn_sched_barrier(0);

    // ---- cross-layer publish: L0 monotone counter (off L0's critical path) ----
    if (layer == 0 && tid == 0)
      atomicAdd(cnt0 + (s << 9) + ((g & 7) << 6), 1);

    // ---- deferred f32 out-stores (off the critical path) ----
    if (!isA) {
#pragma unroll
      for (int nt2 = 0; nt2 < 2; nt2++) {
        const int jg = jgb + (nt2 << 2);
#pragma unroll
        for (int r = 0; r < 4; r++) {
          float hn = hsv[nt2][r];
          float hn2 = __shfl(hn, lane + 1, 64);
          int m = m0 + (hi << 2) + r;
          int idx = (m << 10) + jg;
          if (n < 4 && (n & 1) == 0) {
            if (layer == 1) *(float2*)(out + (size_t)s * BH + idx) = make_float2(hn, hn2);
            else if (s == TT - 1) *(float2*)(out + (size_t)TT * BH + idx) = make_float2(hn, hn2);
          }
          if (s == TT - 1 && n < 4) {
            float cn = creg[nt2][r];
            if (layer == 1) {
              out[(size_t)TT * BH + BH + idx] = hn;        // final h, layer 1
              out[(size_t)TT * BH + 3 * BH + idx] = cn;    // final c, layer 1
            } else {
              out[(size_t)TT * BH + 2 * BH + idx] = cn;    // final c, layer 0
            }
          }
        }
      }
    }
  }
}

extern "C" void kernel_launch(void* const* d_in, const int* in_sizes, int n_in,
                              void* d_out, int out_size, void* d_ws, size_t ws_size,
                              hipStream_t stream) {
  (void)in_sizes; (void)n_in; (void)out_size; (void)ws_size;
  const float* x    = (const float*)d_in[0];
  const float* h0in = (const float*)d_in[1];
  const float* c0in = (const float*)d_in[2];
  const float* W0   = (const float*)d_in[3];
  const float* b0   = (const float*)d_in[4];
  const float* W1   = (const float*)d_in[5];
  const float* b1   = (const float*)d_in[6];
  float* out = (float*)d_out;

  char* ws = (char*)d_ws;
  const size_t HIST = (size_t)(TT + 1) * BH * sizeof(unsigned short);  // 67,239,936 B
  unsigned short* Xbf    = (unsigned short*)(ws);                      // 64 MB
  unsigned short* W0s    = (unsigned short*)(ws + 67108864);           // 16 MB
  unsigned short* W1s    = (unsigned short*)(ws + 83886080);           // 16 MB
  unsigned short* h0hist = (unsigned short*)(ws + 100663296);          // 64.1 MB
  unsigned short* h1hist = (unsigned short*)(ws + 100663296 + HIST);   // 64.1 MB
  unsigned int* tag0     = (unsigned int*)(ws + 100663296 + 2 * HIST); // 32 KB
  unsigned int* tag1     = tag0 + 8192;                                // 32 KB
  int* cnt0              = (int*)(tag1 + 8192);                        // 1 MB

  hipMemsetAsync(tag0, 0, 65536 + (size_t)TT * 512 * sizeof(int), stream);
  cvt_x_kernel<<<2048, 256, 0, stream>>>(x, Xbf);
  cvt_w_kernel<<<4096, 256, 0, stream>>>(W0, W0s);
  cvt_w_kernel<<<4096, 256, 0, stream>>>(W1, W1s);
  init_state_kernel<<<256, 256, 0, stream>>>(h0in, h0hist, h1hist);

  lstm_persist<<<256, 512, 0, stream>>>(W0s, W1s, b0, b1, Xbf,
                                        h0hist, h1hist, c0in, out, tag0, tag1, cnt0);
}

// Round 16
// 4699.079 us; speedup vs baseline: 1.9241x; 1.9241x over previous
//
#include <hip/hip_runtime.h>
#include <hip/hip_bf16.h>
#include <stdint.h>

// Problem constants (fixed by the reference): T=512, B=64, IN=H=1024, L=2
#define TT 512
#define BB 64
#define HH 1024
#define BH 65536    // B*H elements
#define KD 2048     // IN+H == H+H

typedef __attribute__((ext_vector_type(8))) short short8;
typedef __attribute__((ext_vector_type(4))) float f32x4;

__device__ __forceinline__ unsigned short f2bf(float f) {
  union { float f; unsigned int u; } v; v.f = f;
  unsigned int r = v.u + 0x7fffu + ((v.u >> 16) & 1u);  // RNE
  return (unsigned short)(r >> 16);
}
__device__ __forceinline__ float fsig(float x)  { return 1.0f / (1.0f + __expf(-x)); }
__device__ __forceinline__ float ftanhf(float x){ return 1.0f - 2.0f / (__expf(2.0f * x) + 1.0f); }

// ---------------- x -> bf16 ----------------
__global__ void cvt_x_kernel(const float* __restrict__ x, unsigned short* __restrict__ xbf) {
  const int n4 = (TT * BB * 1024) / 4;
  int stride = gridDim.x * blockDim.x;
  for (int i = blockIdx.x * blockDim.x + threadIdx.x; i < n4; i += stride) {
    float4 v = ((const float4*)x)[i];
    unsigned long long p = (unsigned long long)f2bf(v.x)
        | ((unsigned long long)f2bf(v.y) << 16)
        | ((unsigned long long)f2bf(v.z) << 32)
        | ((unsigned long long)f2bf(v.w) << 48);
    ((unsigned long long*)xbf)[i] = p;
  }
}

// ---------------- W [4096][2048] f32 -> bf16, LDS-image layout (TRANSPOSED-C perm) ----
// Ws[g][kk 0..63][nrow 0..31][hi 0..3][8 bf16]  (16B chunks; 128 KB per slice g)
// nrow: nt=nrow>>4, rho=nrow&15 with GATE q=rho&3, COL jl=rho>>2
//   -> W row = q*1024 + g*8 + nt*4 + jl
// (C-row rho = jl*4+q so each lane's acc[0..3] are the 4 gates of ONE h-col.)
// kk<32: k = kk*32 + hi*8 (x-half); kk>=32: k = 1024 + (kk-32)*32 + hi*8 (h-half)
__global__ void cvt_w_kernel(const float* __restrict__ W, unsigned short* __restrict__ Ws) {
  int idx = blockIdx.x * blockDim.x + threadIdx.x;   // < 128*64*32*4 = 1,048,576
  int hi = idx & 3;
  int nr = (idx >> 2) & 31;
  int kk = (idx >> 7) & 63;
  int g  = idx >> 13;
  int q  = nr & 3;            // gate (inner now)
  int jl = (nr >> 2) & 3;     // h-col within 4
  int nt = nr >> 4;
  int grow = (q << 10) + (g << 3) + (nt << 2) + jl;
  int k = ((kk < 32) ? (kk << 5) : (1024 + ((kk - 32) << 5))) + (hi << 3);
  const float* src = W + (size_t)grow * KD + k;
  float4 v0 = ((const float4*)src)[0];
  float4 v1 = ((const float4*)src)[1];
  unsigned long long p0 = (unsigned long long)f2bf(v0.x)
      | ((unsigned long long)f2bf(v0.y) << 16)
      | ((unsigned long long)f2bf(v0.z) << 32)
      | ((unsigned long long)f2bf(v0.w) << 48);
  unsigned long long p1 = (unsigned long long)f2bf(v1.x)
      | ((unsigned long long)f2bf(v1.y) << 16)
      | ((unsigned long long)f2bf(v1.z) << 32)
      | ((unsigned long long)f2bf(v1.w) << 48);
  unsigned long long* dst = (unsigned long long*)(Ws + ((size_t)g << 16) + (kk << 10) + (nr << 5) + (hi << 3));
  dst[0] = p0;
  dst[1] = p1;
}

// ---------------- initial h -> hist slot 0 ----------------
__global__ void init_state_kernel(const float* __restrict__ h0in,
                                  unsigned short* h0s0, unsigned short* h1s0) {
  int i = blockIdx.x * blockDim.x + threadIdx.x;  // < BH
  h0s0[i] = f2bf(h0in[i]);
  h1s0[i] = f2bf(h0in[BH + i]);
}

#define GLD(p)    __hip_atomic_load((p),  __ATOMIC_RELAXED, __HIP_MEMORY_SCOPE_AGENT)
#define GST(p, v) __hip_atomic_store((p), (v), __ATOMIC_RELAXED, __HIP_MEMORY_SCOPE_AGENT)

// spin until the 8 sub-counters (256B apart) sum to 128
__device__ __forceinline__ void poll128(int* base) {
  for (;;) {
    int s = 0;
#pragma unroll
    for (int j = 0; j < 8; j++)
      s += GLD(base + (j << 6));
    if (s >= 128) return;
    __builtin_amdgcn_s_sleep(1);
  }
}

// ---------------- persistent 2-layer LSTM, v11: shfl-free lane-local epilogue ----------------
// 256 blocks x 512 threads, 1 block/CU. Blocks 0-127: layer0, 128-255: layer1.
// TRANSPOSED MFMA: W-slice is the A operand, x/h the B operand; cvt_w permutes
// rows so C-row rho = jl*4 + q. Lane (n,hi) then holds acc[0..3] = the 4 gates
// (i,f,g,o) of h-column (g*8 + nt*4 + hi) for batch row (m0+n): the ENTIRE cell
// update is lane-local (5 exps, zero shfl/ds ops, all 64 lanes active).
// Per-lane operand addressing is unchanged (16x16x32 A/B fragments both index
// by lane&15 / lane>>4), so loads are identical to v8.
// Waves 0-3 (A): dependency-free GEMM one step ahead (L0: x[s+1]; L1: h0[s+2]
// gated lane0-poll cnt0[s+1], monotone) -> partials to LDS dbuf pbuf[(s+1)&1].
// Waves 4-7 (B): tight recurrence: lane0 direct-polls 8-way-split cnt[L][s-1],
// bulk rolling h-loads, 64 dual MFMAs seeded from pbuf, lane-local epilogue,
// 2B sc1 h-stores. Publish: __syncthreads (drain) -> tid0 atomicAdd. f32 out
// stores deferred after the barrier.
__global__ __launch_bounds__(512, 2) void lstm_persist(
    const unsigned short* __restrict__ W0s, const unsigned short* __restrict__ W1s,
    const float* __restrict__ b0, const float* __restrict__ b1,
    const unsigned short* __restrict__ xbf,
    unsigned short* h0hist, unsigned short* h1hist,
    const float* __restrict__ c0in, float* out, int* cnt)
{
  __shared__ short8 wlds[8192];            // 128 KB: [kk 0..63][nrow 0..31][hi 0..3]
  __shared__ f32x4 pbuf[2][4][2][64];      // 16 KB partial double-buffer
  const int tid = threadIdx.x;
  const int bid = blockIdx.x;
  const int layer = bid >> 7;
  const int g = bid & 127;

  const unsigned short* Ws = layer ? W1s : W0s;
  const float* bias = layer ? b1 : b0;
  int* const cnt0 = cnt;                  // cnt0[s], stride 512 ints (8 sub-lines)
  int* const cnt1 = cnt + (TT << 9);      // cnt1[s], stride 512 ints

  // ---- stage weight slice once: linear 128KB copy ----
  {
    const short8* wsrc = (const short8*)(Ws + ((size_t)g << 16));
#pragma unroll
    for (int it = 0; it < 16; it++)
      wlds[tid + (it << 9)] = wsrc[tid + (it << 9)];
  }

  // ---- wave / lane mapping ----
  const int lane = tid & 63;
  const int w  = tid >> 6;        // 0..7
  const bool isA = (w < 4);
  const int mt = w & 3;           // m-tile (batch)
  const int m0 = mt << 4;
  const int n  = lane & 15;       // batch row within tile (C column now)
  const int hi = lane >> 4;       // k-subchunk for operands; h-col within 4 for C
  const short8* bbase0 = wlds + ((n << 2) + hi);          // n-tile 0 rows 0..15
  const short8* bbase1 = wlds + (((16 + n) << 2) + hi);   // n-tile 1 rows 16..31
  const int rowoff = ((m0 + n) << 10) + (hi << 3);        // x/h row base (elements)
  const int m = m0 + n;                                   // this lane's batch row (C)
  const int col0 = (g << 3) + hi;                         // h-col, n-tile 0
  const int col1 = col0 + 4;                              // h-col, n-tile 1

  unsigned short* const myhist = (layer == 0) ? h0hist : h1hist;
  int* const mycnt = (layer == 0) ? cnt0 : cnt1;

  // ---- B-wave state: 4 gate biases per n-tile + c registers ----
  float bq[2][4];
  float creg[2];
  if (!isA) {
#pragma unroll
    for (int nt2 = 0; nt2 < 2; nt2++) {
      int col = nt2 ? col1 : col0;
#pragma unroll
      for (int qg = 0; qg < 4; qg++)
        bq[nt2][qg] = bias[(qg << 10) + col];
      creg[nt2] = c0in[(size_t)layer * BH + (m << 10) + col];
    }
  }
  __syncthreads();   // weights staged

  // ---- prologue: A-waves compute partial[0] (L1 gated lane0-poll cnt0[0]) ----
  if (isA) {
    if (layer == 1) {
      if (lane == 0) poll128(cnt0);
      asm volatile("" ::: "memory");
    }
    const unsigned short* asrc = ((layer == 0) ? xbf : h0hist + (size_t)BH) + rowoff;
    short8 ha[8];
#pragma unroll
    for (int j = 0; j < 8; j++) ha[j] = *(const short8*)(asrc + (j << 5));
    f32x4 a0 = {0.f, 0.f, 0.f, 0.f}, a1 = {0.f, 0.f, 0.f, 0.f};
#pragma unroll
    for (int blk = 0; blk < 4; blk++) {
#pragma unroll
      for (int j = 0; j < 8; j++) {
        int kk = (blk << 3) + j;
        a0 = __builtin_amdgcn_mfma_f32_16x16x32_bf16(bbase0[kk << 7], ha[j], a0, 0, 0, 0);
        a1 = __builtin_amdgcn_mfma_f32_16x16x32_bf16(bbase1[kk << 7], ha[j], a1, 0, 0, 0);
        if (blk < 3) ha[j] = *(const short8*)(asrc + ((kk + 8) << 5));
      }
    }
    pbuf[0][mt][0][lane] = a0;
    pbuf[0][mt][1][lane] = a1;
  }
  __syncthreads();   // partial[0] sealed

  for (int s = 0; s < TT; s++) {
    float hsv[2];   // B: saved h outputs for deferred f32 out-stores

    if (isA) {
      // ---- A-compute for step s+1 into pbuf[(s+1)&1] ----
      if (s + 1 < TT) {
        if (layer == 1) {
          if (lane == 0) poll128(cnt0 + ((s + 1) << 9));   // h0hist[s+2] ready
          asm volatile("" ::: "memory");
        }
        const unsigned short* asrc = ((layer == 0) ? xbf + (size_t)(s + 1) * BH
                                                   : h0hist + (size_t)(s + 2) * BH) + rowoff;
        short8 ha[8];
#pragma unroll
        for (int j = 0; j < 8; j++) ha[j] = *(const short8*)(asrc + (j << 5));
        f32x4 a0 = {0.f, 0.f, 0.f, 0.f}, a1 = {0.f, 0.f, 0.f, 0.f};
#pragma unroll
        for (int blk = 0; blk < 4; blk++) {
#pragma unroll
          for (int j = 0; j < 8; j++) {
            int kk = (blk << 3) + j;
            a0 = __builtin_amdgcn_mfma_f32_16x16x32_bf16(bbase0[kk << 7], ha[j], a0, 0, 0, 0);
            a1 = __builtin_amdgcn_mfma_f32_16x16x32_bf16(bbase1[kk << 7], ha[j], a1, 0, 0, 0);
            if (blk < 3) ha[j] = *(const short8*)(asrc + ((kk + 8) << 5));
          }
        }
        int buf = (s + 1) & 1;
        pbuf[buf][mt][0][lane] = a0;
        pbuf[buf][mt][1][lane] = a1;
      }
    } else {
      // ---- B tight wait: lane0 of THIS wave polls split counters directly ----
      if (s >= 1) {
        if (lane == 0) poll128(mycnt + ((s - 1) << 9));
        asm volatile("" ::: "memory");   // no load hoisting above the spin
      }
      // ---- recurrent GEMM: h[s] x second K-half (8-deep rolling) ----
      f32x4 acc0 = pbuf[s & 1][mt][0][lane];
      f32x4 acc1 = pbuf[s & 1][mt][1][lane];
      const unsigned short* inB = myhist + (size_t)s * BH + rowoff;
      short8 ha[8];
#pragma unroll
      for (int j = 0; j < 8; j++) ha[j] = *(const short8*)(inB + (j << 5));
#pragma unroll
      for (int blk = 0; blk < 4; blk++) {
#pragma unroll
        for (int j = 0; j < 8; j++) {
          int kk = (blk << 3) + j;
          acc0 = __builtin_amdgcn_mfma_f32_16x16x32_bf16(bbase0[(32 + kk) << 7], ha[j], acc0, 0, 0, 0);
          acc1 = __builtin_amdgcn_mfma_f32_16x16x32_bf16(bbase1[(32 + kk) << 7], ha[j], acc1, 0, 0, 0);
          if (blk < 3) ha[j] = *(const short8*)(inB + ((kk + 8) << 5));
        }
      }

      // ---- epilogue: LANE-LOCAL cell update (zero cross-lane), 2B sc1 h-stores ----
      unsigned short* hb = myhist + (size_t)(s + 1) * BH;
#pragma unroll
      for (int nt2 = 0; nt2 < 2; nt2++) {
        f32x4 acc = nt2 ? acc1 : acc0;
        const int col = nt2 ? col1 : col0;
        float ig = fsig(acc[0] + bq[nt2][0]);
        float fg = fsig(acc[1] + bq[nt2][1]);
        float gg = ftanhf(acc[2] + bq[nt2][2]);
        float og = fsig(acc[3] + bq[nt2][3]);
        float cn = ig * gg + fg * creg[nt2];
        float hn = og * ftanhf(cn);
        creg[nt2] = cn;
        hsv[nt2] = hn;
        GST(hb + (m << 10) + col, f2bf(hn));
      }
    }

    // ---- end of step: seal pbuf[(s+1)&1], drain B h-stores, publish ----
    __syncthreads();
    if (tid == 0) atomicAdd(mycnt + (s << 9) + ((g & 7) << 6), 1);

    // ---- deferred f32 out-stores (off the critical drain) ----
    if (!isA) {
#pragma unroll
      for (int nt2 = 0; nt2 < 2; nt2++) {
        const int col = nt2 ? col1 : col0;
        const int idx = (m << 10) + col;
        float hn = hsv[nt2];
        if (layer == 1) {
          out[(size_t)s * BH + idx] = hn;                  // hlast[s]
          if (s == TT - 1) {
            out[(size_t)TT * BH + BH + idx] = hn;          // final h, layer 1
            out[(size_t)TT * BH + 3 * BH + idx] = creg[nt2];  // final c, layer 1
          }
        } else if (s == TT - 1) {
          out[(size_t)TT * BH + idx] = hn;                 // final h, layer 0
          out[(size_t)TT * BH + 2 * BH + idx] = creg[nt2]; // final c, layer 0
        }
      }
    }
  }
}

extern "C" void kernel_launch(void* const* d_in, const int* in_sizes, int n_in,
                              void* d_out, int out_size, void* d_ws, size_t ws_size,
                              hipStream_t stream) {
  (void)in_sizes; (void)n_in; (void)out_size; (void)ws_size;
  const float* x    = (const float*)d_in[0];
  const float* h0in = (const float*)d_in[1];
  const float* c0in = (const float*)d_in[2];
  const float* W0   = (const float*)d_in[3];
  const float* b0   = (const float*)d_in[4];
  const float* W1   = (const float*)d_in[5];
  const float* b1   = (const float*)d_in[6];
  float* out = (float*)d_out;

  char* ws = (char*)d_ws;
  const size_t HIST = (size_t)(TT + 1) * BH * sizeof(unsigned short);  // 67,239,936 B
  unsigned short* Xbf    = (unsigned short*)(ws);                      // 64 MB
  unsigned short* W0s    = (unsigned short*)(ws + 67108864);           // 16 MB
  unsigned short* W1s    = (unsigned short*)(ws + 83886080);           // 16 MB
  unsigned short* h0hist = (unsigned short*)(ws + 100663296);          // 64.1 MB
  unsigned short* h1hist = (unsigned short*)(ws + 100663296 + HIST);   // 64.1 MB
  int* cnt               = (int*)(ws + 100663296 + 2 * HIST);          // 2 MB counters

  const size_t CNT_BYTES = (size_t)2 * TT * 512 * sizeof(int);
  hipMemsetAsync(cnt, 0, CNT_BYTES, stream);
  cvt_x_kernel<<<2048, 256, 0, stream>>>(x, Xbf);
  cvt_w_kernel<<<4096, 256, 0, stream>>>(W0, W0s);
  cvt_w_kernel<<<4096, 256, 0, stream>>>(W1, W1s);
  init_state_kernel<<<256, 256, 0, stream>>>(h0in, h0hist, h1hist);

  lstm_persist<<<256, 512, 0, stream>>>(W0s, W1s, b0, b1, Xbf,
                                        h0hist, h1hist, c0in, out, cnt);
}